// Round 12
// baseline (411.270 us; speedup 1.0000x reference)
//
#include <hip/hip_runtime.h>
#include <math.h>

#define T_DIM 2048
#define C_DIM 1024
#define H_DIM 16
#define HD 64
#define TOPK_K 64
#define LCAP 128
#define STRIPE 512

typedef __attribute__((ext_vector_type(8))) __bf16 bf16x8;
typedef __attribute__((ext_vector_type(4))) float f32x4;

__device__ __forceinline__ unsigned short bf16rn(float x) {
  unsigned u = __float_as_uint(x);
  return (unsigned short)((u + 0x7FFFu + ((u >> 16) & 1u)) >> 16);
}
__device__ __forceinline__ unsigned f2u(float f) {
  unsigned u = __float_as_uint(f);
  return (u & 0x80000000u) ? ~u : (u | 0x80000000u);
}
__device__ __forceinline__ float u2f(unsigned u) {
  unsigned v = (u & 0x80000000u) ? (u & 0x7FFFFFFFu) : ~u;
  return __uint_as_float(v);
}
__device__ __forceinline__ bf16x8 ld_frag(const uint4* p) {
  uint4 u = *p;
  return __builtin_bit_cast(bf16x8, u);
}
#define PAD_KEY 0x007FFFFFu   // f2u(-INF); real raw scores always exceed this

// ------- fused fp32 -> frag-global bf16 hi/lo converter + rope table --------
__global__ __launch_bounds__(256) void convert_all_kernel(
    const float* __restrict__ x, const float* __restrict__ wa,
    const float* __restrict__ wg, const float* __restrict__ wp,
    unsigned short* __restrict__ xh, unsigned short* __restrict__ xl,
    unsigned short* __restrict__ wqgh, unsigned short* __restrict__ wqgl,
    unsigned short* __restrict__ wph, unsigned short* __restrict__ wpl,
    float2* __restrict__ tab)
{
  const int tid = blockIdx.x * 256 + threadIdx.x;
  const int k8 = tid & 127, r = tid >> 7;
  if (r >= 7168) {   // rope sincos table tail: 512 r-slots x 128 = 65536
    const int e = ((r - 7168) << 7) | k8;
    const int t = e >> 5, d = e & 31;
    double invf = exp(-(double)d * (log(10000.0) / 32.0));
    double ang = (double)t * invf;
    tab[e] = make_float2((float)cos(ang), (float)sin(ang));
    return;
  }
  const float* src;
  unsigned short *Dh, *Dl;
  int srow, drow;
  if (r < 2048)      { src = x;  Dh = xh;   Dl = xl;   srow = r;        drow = r; }
  else if (r < 5120) { src = wa; Dh = wqgh; Dl = wqgl; srow = r - 2048; drow = r - 2048; }
  else if (r < 6144) { src = wg; Dh = wqgh; Dl = wqgl; srow = r - 5120; drow = r - 2048; }
  else               { src = wp; Dh = wph;  Dl = wpl;  srow = r - 6144; drow = r - 6144; }
  const float* s = src + ((size_t)srow << 10) + (k8 << 3);
  float4 a = *(const float4*)s;
  float4 b = *(const float4*)(s + 4);
  float xs[8] = {a.x, a.y, a.z, a.w, b.x, b.y, b.z, b.w};
  unsigned hi[8], lo[8];
#pragma unroll
  for (int jj = 0; jj < 8; ++jj) {
    unsigned short hb = bf16rn(xs[jj]);
    hi[jj] = hb;
    lo[jj] = bf16rn(xs[jj] - __uint_as_float((unsigned)hb << 16));
  }
  const int t16 = drow >> 4, rr = drow & 15, kc = k8 >> 2, kq = k8 & 3;
  const size_t elem = (((size_t)(t16 * 32 + kc)) * 64 + ((kq << 4) | rr)) * 8;
  uint4 vh, vl;
  vh.x = hi[0] | (hi[1] << 16); vh.y = hi[2] | (hi[3] << 16);
  vh.z = hi[4] | (hi[5] << 16); vh.w = hi[6] | (hi[7] << 16);
  vl.x = lo[0] | (lo[1] << 16); vl.y = lo[2] | (lo[3] << 16);
  vl.z = lo[4] | (lo[5] << 16); vl.w = lo[6] | (lo[7] << 16);
  *(uint4*)(Dh + elem) = vh;
  *(uint4*)(Dl + elem) = vl;
}

// ---------------- split-bf16 MFMA GEMM machinery ----------------
__device__ __forceinline__ void gld_lds16(const unsigned short* g, unsigned short* l) {
  __builtin_amdgcn_global_load_lds(
      (const __attribute__((address_space(1))) unsigned int*)g,
      (__attribute__((address_space(3))) unsigned int*)l, 16, 0, 0);
}

__global__ __launch_bounds__(256, 2) void mgemm_qkvg_kernel(
    const unsigned short* __restrict__ Ah, const unsigned short* __restrict__ Al,
    const unsigned short* __restrict__ Bh, const unsigned short* __restrict__ Bl,
    float* __restrict__ Cq, float* __restrict__ Ck, float* __restrict__ Cv,
    float* __restrict__ Cg)
{
  __shared__ __align__(16) unsigned short As[2 * 8 * 512];
  __shared__ __align__(16) unsigned short Bs[2 * 8 * 512];
  const int tid = threadIdx.x, lane = tid & 63, w = tid >> 6;
  const int mt0 = blockIdx.y << 3;
  const int nt0 = blockIdx.x << 3;

  f32x4 acc[4][4];
#pragma unroll
  for (int i = 0; i < 4; ++i)
#pragma unroll
    for (int j = 0; j < 4; ++j)
      acc[i][j] = (f32x4){0.f, 0.f, 0.f, 0.f};

  const int rA = (w >> 1) << 2, rB = (w & 1) << 2;

  for (int kc = 0; kc < 32; ++kc) {
#pragma unroll
    for (int li = 0; li < 8; ++li) {
      const int gi = (w << 3) | li;
      const int t = gi & 7, hl = (gi >> 3) & 1, mat = gi >> 4;
      const unsigned short* gbase = mat ? (hl ? Bl : Bh) : (hl ? Al : Ah);
      const int tg = (mat ? nt0 : mt0) + t;
      const unsigned short* g = gbase + (((size_t)(tg * 32 + kc) << 6) + lane) * 8;
      unsigned short* l = (mat ? Bs : As) + hl * 4096 + t * 512;
      gld_lds16(g, l);
    }
    __syncthreads();
    bf16x8 ah[4], al[4], bh[4], bl[4];
#pragma unroll
    for (int i = 0; i < 4; ++i) {
      ah[i] = *(const bf16x8*)&As[(rA + i) * 512 + lane * 8];
      al[i] = *(const bf16x8*)&As[4096 + (rA + i) * 512 + lane * 8];
      bh[i] = *(const bf16x8*)&Bs[(rB + i) * 512 + lane * 8];
      bl[i] = *(const bf16x8*)&Bs[4096 + (rB + i) * 512 + lane * 8];
    }
#pragma unroll
    for (int i = 0; i < 4; ++i)
#pragma unroll
      for (int j = 0; j < 4; ++j) {
        acc[i][j] = __builtin_amdgcn_mfma_f32_16x16x32_bf16(ah[i], bh[j], acc[i][j], 0, 0, 0);
        acc[i][j] = __builtin_amdgcn_mfma_f32_16x16x32_bf16(ah[i], bl[j], acc[i][j], 0, 0, 0);
        acc[i][j] = __builtin_amdgcn_mfma_f32_16x16x32_bf16(al[i], bh[j], acc[i][j], 0, 0, 0);
      }
    __syncthreads();
  }

  const int col = lane & 15, quad = lane >> 4;
  const int mbase = (blockIdx.y << 7) + ((w >> 1) << 6);
  const int nbase = (blockIdx.x << 7) + ((w & 1) << 6);
  const int which = nbase >> 10;
  if (which < 3) {
    const int h = (nbase & 1023) >> 6;
    float* dst = (which == 0) ? Cq : (which == 1) ? Ck : Cv;
    float* base = dst + (((size_t)h * T_DIM) << 6);
#pragma unroll
    for (int i = 0; i < 4; ++i)
#pragma unroll
      for (int j = 0; j < 4; ++j)
#pragma unroll
        for (int reg = 0; reg < 4; ++reg) {
          const int m = mbase + i * 16 + quad * 4 + reg;
          base[((size_t)m << 6) + j * 16 + col] = acc[i][j][reg];
        }
  } else {
    const int cb = nbase & 1023;
#pragma unroll
    for (int i = 0; i < 4; ++i)
#pragma unroll
      for (int j = 0; j < 4; ++j)
#pragma unroll
        for (int reg = 0; reg < 4; ++reg) {
          const int m = mbase + i * 16 + quad * 4 + reg;
          float vv = acc[i][j][reg];
          Cg[((size_t)m << 10) + cb + j * 16 + col] = vv / (1.f + expf(-vv));
        }
  }
}

// proj GEMM, split-K x4: kc in [z*8, z*8+8)
__global__ __launch_bounds__(256, 2) void mgemm_proj_kernel(
    const unsigned short* __restrict__ Ah, const unsigned short* __restrict__ Al,
    const unsigned short* __restrict__ Bh, const unsigned short* __restrict__ Bl,
    float* __restrict__ P0, float* __restrict__ P1,
    float* __restrict__ P2, float* __restrict__ P3)
{
  __shared__ __align__(16) unsigned short As[2 * 8 * 512];
  __shared__ __align__(16) unsigned short Bs[2 * 8 * 512];
  const int tid = threadIdx.x, lane = tid & 63, w = tid >> 6;
  const int mt0 = blockIdx.y << 3;
  const int nt0 = blockIdx.x << 3;
  const int kc0 = blockIdx.z << 3;
  float* Cout = (blockIdx.z == 0) ? P0 : (blockIdx.z == 1) ? P1
              : (blockIdx.z == 2) ? P2 : P3;

  f32x4 acc[4][4];
#pragma unroll
  for (int i = 0; i < 4; ++i)
#pragma unroll
    for (int j = 0; j < 4; ++j)
      acc[i][j] = (f32x4){0.f, 0.f, 0.f, 0.f};

  const int rA = (w >> 1) << 2, rB = (w & 1) << 2;

  for (int kc = kc0; kc < kc0 + 8; ++kc) {
#pragma unroll
    for (int li = 0; li < 8; ++li) {
      const int gi = (w << 3) | li;
      const int t = gi & 7, hl = (gi >> 3) & 1, mat = gi >> 4;
      const unsigned short* gbase = mat ? (hl ? Bl : Bh) : (hl ? Al : Ah);
      const int tg = (mat ? nt0 : mt0) + t;
      const unsigned short* g = gbase + (((size_t)(tg * 32 + kc) << 6) + lane) * 8;
      unsigned short* l = (mat ? Bs : As) + hl * 4096 + t * 512;
      gld_lds16(g, l);
    }
    __syncthreads();
    bf16x8 ah[4], al[4], bh[4], bl[4];
#pragma unroll
    for (int i = 0; i < 4; ++i) {
      ah[i] = *(const bf16x8*)&As[(rA + i) * 512 + lane * 8];
      al[i] = *(const bf16x8*)&As[4096 + (rA + i) * 512 + lane * 8];
      bh[i] = *(const bf16x8*)&Bs[(rB + i) * 512 + lane * 8];
      bl[i] = *(const bf16x8*)&Bs[4096 + (rB + i) * 512 + lane * 8];
    }
#pragma unroll
    for (int i = 0; i < 4; ++i)
#pragma unroll
      for (int j = 0; j < 4; ++j) {
        acc[i][j] = __builtin_amdgcn_mfma_f32_16x16x32_bf16(ah[i], bh[j], acc[i][j], 0, 0, 0);
        acc[i][j] = __builtin_amdgcn_mfma_f32_16x16x32_bf16(ah[i], bl[j], acc[i][j], 0, 0, 0);
        acc[i][j] = __builtin_amdgcn_mfma_f32_16x16x32_bf16(al[i], bh[j], acc[i][j], 0, 0, 0);
      }
    __syncthreads();
  }

  const int col = lane & 15, quad = lane >> 4;
  const int mbase = (blockIdx.y << 7) + ((w >> 1) << 6);
  const int nbase = (blockIdx.x << 7) + ((w & 1) << 6);
#pragma unroll
  for (int i = 0; i < 4; ++i)
#pragma unroll
    for (int j = 0; j < 4; ++j)
#pragma unroll
      for (int reg = 0; reg < 4; ++reg) {
        const int m = mbase + i * 16 + quad * 4 + reg;
        Cout[((size_t)m << 10) + nbase + j * 16 + col] = acc[i][j][reg];
      }
}

__global__ __launch_bounds__(256) void add4_kernel(
    const float* __restrict__ P0, const float* __restrict__ P1,
    const float* __restrict__ P2, const float* __restrict__ P3,
    float* __restrict__ out)
{
  const int i = (blockIdx.x * 256 + threadIdx.x) << 2;
  float4 a = *(const float4*)(P0 + i);
  float4 b = *(const float4*)(P1 + i);
  float4 c = *(const float4*)(P2 + i);
  float4 d = *(const float4*)(P3 + i);
  float4 o = {a.x + b.x + c.x + d.x, a.y + b.y + c.y + d.y,
              a.z + b.z + c.z + d.z, a.w + b.w + c.w + d.w};
  *(float4*)(out + i) = o;
}

// ------- RoPE (table-driven) + bf16 hi/lo split into attention frag layout --
__global__ __launch_bounds__(64) void prep_frag_kernel(
    float* __restrict__ qb, float* __restrict__ kb,
    const float2* __restrict__ tab)
{
  float* buf = blockIdx.z ? kb : qb;
  const int lane = threadIdx.x;
  const int t16 = blockIdx.x, h = blockIdx.y;
  const int nr = lane & 15, quad = lane >> 4;
  const int t = (t16 << 4) + nr;
  const float* row = buf + ((size_t)(h * T_DIM + t) << 6);
  const int d0 = quad << 3;
  float4 a0 = *(const float4*)(row + d0);
  float4 a1 = *(const float4*)(row + d0 + 4);
  float4 b0 = *(const float4*)(row + 32 + d0);
  float4 b1 = *(const float4*)(row + 32 + d0 + 4);
  float x0[8] = {a0.x, a0.y, a0.z, a0.w, a1.x, a1.y, a1.z, a1.w};
  float x1[8] = {b0.x, b0.y, b0.z, b0.w, b1.x, b1.y, b1.z, b1.w};
  const float2* tb = tab + t * 32 + d0;
  unsigned short h0[8], l0[8], h1[8], l1[8];
#pragma unroll
  for (int jj = 0; jj < 8; ++jj) {
    float2 cs2 = tb[jj];
    float o0 = fmaf(x0[jj], cs2.x, -x1[jj] * cs2.y);
    float o1 = fmaf(x1[jj], cs2.x, x0[jj] * cs2.y);
    unsigned short hb = bf16rn(o0);
    h0[jj] = hb;
    l0[jj] = bf16rn(o0 - __uint_as_float((unsigned)hb << 16));
    hb = bf16rn(o1);
    h1[jj] = hb;
    l1[jj] = bf16rn(o1 - __uint_as_float((unsigned)hb << 16));
  }
  char* base = (char*)buf + (((size_t)(h * 128 + t16)) << 12);
  uint4 v;
  v.x = (unsigned)h0[0] | ((unsigned)h0[1] << 16);
  v.y = (unsigned)h0[2] | ((unsigned)h0[3] << 16);
  v.z = (unsigned)h0[4] | ((unsigned)h0[5] << 16);
  v.w = (unsigned)h0[6] | ((unsigned)h0[7] << 16);
  ((uint4*)base)[lane] = v;
  v.x = (unsigned)h1[0] | ((unsigned)h1[1] << 16);
  v.y = (unsigned)h1[2] | ((unsigned)h1[3] << 16);
  v.z = (unsigned)h1[4] | ((unsigned)h1[5] << 16);
  v.w = (unsigned)h1[6] | ((unsigned)h1[7] << 16);
  ((uint4*)(base + 1024))[lane] = v;
  v.x = (unsigned)l0[0] | ((unsigned)l0[1] << 16);
  v.y = (unsigned)l0[2] | ((unsigned)l0[3] << 16);
  v.z = (unsigned)l0[4] | ((unsigned)l0[5] << 16);
  v.w = (unsigned)l0[6] | ((unsigned)l0[7] << 16);
  ((uint4*)(base + 2048))[lane] = v;
  v.x = (unsigned)l1[0] | ((unsigned)l1[1] << 16);
  v.y = (unsigned)l1[2] | ((unsigned)l1[3] << 16);
  v.z = (unsigned)l1[4] | ((unsigned)l1[5] << 16);
  v.w = (unsigned)l1[6] | ((unsigned)l1[7] << 16);
  ((uint4*)(base + 3072))[lane] = v;
}

// -------- score GEMM: keys S[h][q-qbase][j] = f2u(raw score), full-util MFMA.
// Block = 16 queries (tile16) x 256 cols; wave w covers jt16 = jt256*16+jj*4+w.
// No LDS, no barriers. Causal blocks/tiles skipped. Stripe = 512 queries so
// the 64 MB key buffer stays L3-resident between score and select.
__global__ __launch_bounds__(256) void score_kernel(
    const float* __restrict__ qfrag, const float* __restrict__ kfrag,
    unsigned* __restrict__ S, int qbase)
{
  const int lane = threadIdx.x & 63, w = threadIdx.x >> 6;
  const int jt256 = blockIdx.x;          // [0,8)
  const int qtL = blockIdx.y;            // local tile16 in stripe [0,32)
  const int h = blockIdx.z;
  const int qt = (qbase >> 4) + qtL;     // global tile16
  if ((jt256 << 4) > qt) return;         // whole block above diagonal
  const uint4* qf = (const uint4*)((const char*)qfrag + (((size_t)(h * 128 + qt)) << 12));
  bf16x8 Ah0 = ld_frag(qf + lane);
  bf16x8 Ah1 = ld_frag(qf + 64 + lane);
  bf16x8 Al0 = ld_frag(qf + 128 + lane);
  bf16x8 Al1 = ld_frag(qf + 192 + lane);
  const int col = lane & 15, quad = lane >> 4;
  unsigned* Sh = S + (((size_t)(h * STRIPE)) << 11);   // rows of 2048
#pragma unroll
  for (int jj = 0; jj < 4; ++jj) {
    const int jt16 = (jt256 << 4) + (jj << 2) + w;
    if (jt16 > qt) continue;             // tile entirely above diagonal
    const uint4* kf = (const uint4*)((const char*)kfrag + (((size_t)(h * 128 + jt16)) << 12));
    bf16x8 Bh0 = ld_frag(kf + lane);
    bf16x8 Bh1 = ld_frag(kf + 64 + lane);
    bf16x8 Bl0 = ld_frag(kf + 128 + lane);
    bf16x8 Bl1 = ld_frag(kf + 192 + lane);
    f32x4 acc = {0.f, 0.f, 0.f, 0.f};
    acc = __builtin_amdgcn_mfma_f32_16x16x32_bf16(Ah0, Bh0, acc, 0, 0, 0);
    acc = __builtin_amdgcn_mfma_f32_16x16x32_bf16(Ah0, Bl0, acc, 0, 0, 0);
    acc = __builtin_amdgcn_mfma_f32_16x16x32_bf16(Al0, Bh0, acc, 0, 0, 0);
    acc = __builtin_amdgcn_mfma_f32_16x16x32_bf16(Ah1, Bh1, acc, 0, 0, 0);
    acc = __builtin_amdgcn_mfma_f32_16x16x32_bf16(Ah1, Bl1, acc, 0, 0, 0);
    acc = __builtin_amdgcn_mfma_f32_16x16x32_bf16(Al1, Bh1, acc, 0, 0, 0);
    const int jcol = (jt16 << 4) + col;
#pragma unroll
    for (int reg = 0; reg < 4; ++reg) {
      const int qrL = (qtL << 4) + quad * 4 + reg;   // row in stripe
      Sh[(((size_t)qrL) << 11) + jcol] = f2u(acc[reg]);
    }
  }
}

// -------- select: one wave per query; radix-select + span + PV. No barriers.
__global__ __launch_bounds__(256) void select_kernel(
    const unsigned* __restrict__ S, const float* __restrict__ v,
    const float* __restrict__ span_params, float* __restrict__ y, int qbase)
{
  __shared__ unsigned histB[4 * 256];   // per-wave 1 KB
  __shared__ int listJB[4 * LCAP];
  __shared__ unsigned listUB[4 * LCAP];

  const int lane = threadIdx.x & 63;
  const int w = threadIdx.x >> 6;
  const int bx = gridDim.x - 1 - blockIdx.x;       // LPT: heavy queries first
  const int qi = qbase + (bx << 2) + w;
  const int h = blockIdx.y;
  const int n = qi + 1;
  const float* vh = v + (((size_t)h * T_DIM) << 6);
  const unsigned* srow = S + (((size_t)(h * STRIPE + (qi - qbase))) << 11);

  // ---- load keys: 8 chunks of 256; lane reads uint4 at chunk*256 + lane*4 ----
  unsigned uk[32];
#pragma unroll
  for (int cc = 0; cc < 8; ++cc) {
    const int jb = (cc << 8) + (lane << 2);
    if ((cc << 8) < n) {
      uint4 u4 = *(const uint4*)(srow + jb);
      uk[4 * cc + 0] = (jb + 0 < n) ? u4.x : PAD_KEY;
      uk[4 * cc + 1] = (jb + 1 < n) ? u4.y : PAD_KEY;
      uk[4 * cc + 2] = (jb + 2 < n) ? u4.z : PAD_KEY;
      uk[4 * cc + 3] = (jb + 3 < n) ? u4.w : PAD_KEY;
    } else {
      uk[4 * cc + 0] = PAD_KEY; uk[4 * cc + 1] = PAD_KEY;
      uk[4 * cc + 2] = PAD_KEY; uk[4 * cc + 3] = PAD_KEY;
    }
  }

  unsigned* hist = histB + (w << 8);
  int* listJ = listJB + (w << 7);
  unsigned* listU = listUB + (w << 7);
  const float span = 2048.f * fminf(fmaxf(span_params[h], 0.f), 1.f);

  // ---- row max ----
  unsigned umax = 0;
#pragma unroll
  for (int i = 0; i < 32; ++i) umax = max(umax, uk[i]);
#pragma unroll
  for (int off = 32; off > 0; off >>= 1)
    umax = max(umax, (unsigned)__shfl_xor((int)umax, off, 64));
  const float mraw = u2f(umax);

  // ---- exact rank-64 threshold: radix-256 select with early exit ----
  unsigned thresh_u = 0;
  if (n > TOPK_K) {
    unsigned prefix = 0;
    unsigned want = TOPK_K;
    for (int shift = 24; shift >= 0; shift -= 8) {
      uint4 z4 = {0u, 0u, 0u, 0u};
      *(uint4*)&hist[lane << 2] = z4;
      __threadfence_block();
      const unsigned pm = (shift == 24) ? 0u : (0xFFFFFFFFu << (shift + 8));
#pragma unroll
      for (int cc = 0; cc < 8; ++cc) {
        if ((cc << 8) < n) {
#pragma unroll
          for (int e = 0; e < 4; ++e) {
            const unsigned u = uk[4 * cc + e];
            if (u > PAD_KEY && (u & pm) == prefix)
              atomicAdd(&hist[(u >> shift) & 255u], 1u);
          }
        }
      }
      __threadfence_block();
      uint4 hv = *(const uint4*)&hist[lane << 2];
      unsigned loc = hv.x + hv.y + hv.z + hv.w;
      unsigned suf = loc;
#pragma unroll
      for (int off = 1; off < 64; off <<= 1) {
        unsigned t = __shfl_down(suf, off, 64);
        suf += (lane + off < 64) ? t : 0u;
      }
      unsigned sufE = suf - loc;
      unsigned S3 = sufE + hv.w;
      unsigned S2 = S3 + hv.z;
      unsigned S1 = S2 + hv.y;
      unsigned S0 = S1 + hv.x;
      const unsigned wt = want;
      int found = 0;
      unsigned pk = 0;
      if (S0 >= wt && S1 < wt)
        { found = 1; pk = ((unsigned)(4*lane+0) << 16) | ((S0 == wt) ? 0x8000u : 0u) | (wt - S1); }
      if (S1 >= wt && S2 < wt)
        { found = 1; pk = ((unsigned)(4*lane+1) << 16) | ((S1 == wt) ? 0x8000u : 0u) | (wt - S2); }
      if (S2 >= wt && S3 < wt)
        { found = 1; pk = ((unsigned)(4*lane+2) << 16) | ((S2 == wt) ? 0x8000u : 0u) | (wt - S3); }
      if (S3 >= wt && sufE < wt)
        { found = 1; pk = ((unsigned)(4*lane+3) << 16) | ((S3 == wt) ? 0x8000u : 0u) | (wt - sufE); }
      unsigned long long mk = __ballot(found);
      int src = __ffsll(mk) - 1;
      pk = __shfl(pk, src, 64);
      prefix |= (pk >> 16) << shift;
      want = pk & 0x7FFFu;
      if (pk & 0x8000u) break;
    }
    thresh_u = prefix;
  }

  // ---- compact kept (topk) elements: ballot append of (j, ukey) ----
  int cnt_run = 0;
#pragma unroll
  for (int cc = 0; cc < 8; ++cc) {
    if ((cc << 8) < n) {
#pragma unroll
      for (int e = 0; e < 4; ++e) {
        const int j = (cc << 8) + (lane << 2) + e;
        const unsigned u = uk[4 * cc + e];
        const bool keep = (u >= thresh_u) && (u > PAD_KEY);
        unsigned long long mb = __ballot(keep);
        if (keep) {
          int pos = cnt_run + (int)__popcll(mb & ((1ull << lane) - 1ull));
          if (pos < LCAP) { listJ[pos] = j; listU[pos] = u; }
        }
        cnt_run += (int)__popcll(mb);
      }
    }
  }
  const int cnt = min(cnt_run, LCAP);
  __threadfence_block();

  // ---- heavy math on ~64 kept elements ----
  float Zl = 0.f, Ul = 0.f;
  for (int e = lane; e < cnt; e += 64) {
    const unsigned u = listU[e];
    const int j = listJ[e];
    const float wv = __expf((u2f(u) - mraw) * 0.125f);
    const float dist = (float)(qi - j);
    const float msk = fminf(fmaxf((32.f + span - dist) * (1.f / 32.f), 0.f), 1.f);
    const float wm = wv * msk;
    Zl += wv;
    Ul += wm;
    listU[e] = __float_as_uint(wm);
  }
#pragma unroll
  for (int off = 32; off > 0; off >>= 1) {
    Zl += __shfl_xor(Zl, off, 64);
    Ul += __shfl_xor(Ul, off, 64);
  }
  const float scale = 1.f / (Ul + 1e-8f * Zl);
  __threadfence_block();

  // ---- PV over kept list: 4 rows x 16 dim-groups per iteration ----
  const int g = lane >> 4;
  const int d4 = (lane & 15) << 2;
  float4 acc4 = {0.f, 0.f, 0.f, 0.f};
  for (int e0 = 0; e0 < cnt; e0 += 4) {
    int e = e0 + g;
    float wm = 0.f;
    int idx = 0;
    if (e < cnt) { idx = listJ[e]; wm = __uint_as_float(listU[e]); }
    const float4 vv = *(const float4*)(vh + ((size_t)idx << 6) + d4);
    acc4.x = fmaf(wm, vv.x, acc4.x);
    acc4.y = fmaf(wm, vv.y, acc4.y);
    acc4.z = fmaf(wm, vv.z, acc4.z);
    acc4.w = fmaf(wm, vv.w, acc4.w);
  }
#pragma unroll
  for (int off = 16; off <= 32; off <<= 1) {
    acc4.x += __shfl_xor(acc4.x, off, 64);
    acc4.y += __shfl_xor(acc4.y, off, 64);
    acc4.z += __shfl_xor(acc4.z, off, 64);
    acc4.w += __shfl_xor(acc4.w, off, 64);
  }
  if (g == 0) {
    float4 o = {acc4.x * scale, acc4.y * scale, acc4.z * scale, acc4.w * scale};
    *(float4*)(y + ((((size_t)h * T_DIM) + qi) << 6) + d4) = o;
  }
}

// -------- gating: y_att (head-major) * gate -> ygf frag-global hi/lo --------
__global__ __launch_bounds__(256) void gate_mul_frag_kernel(
    const float* __restrict__ y_att, const float* __restrict__ gate,
    unsigned short* __restrict__ Yh, unsigned short* __restrict__ Yl)
{
  const int tid = blockIdx.x * 256 + threadIdx.x;
  const int k8 = tid & 127, r = tid >> 7;
  const int c0 = k8 << 3;
  const int h = c0 >> 6, d0 = c0 & 63;
  const float* ya = y_att + ((size_t)(h * T_DIM + r) << 6) + d0;
  const float* ga = gate + ((size_t)r << 10) + c0;
  float4 y0 = *(const float4*)ya;
  float4 y1 = *(const float4*)(ya + 4);
  float4 g0 = *(const float4*)ga;
  float4 g1 = *(const float4*)(ga + 4);
  float p[8] = {y0.x * g0.x, y0.y * g0.y, y0.z * g0.z, y0.w * g0.w,
                y1.x * g1.x, y1.y * g1.y, y1.z * g1.z, y1.w * g1.w};
  unsigned hi[8], lo[8];
#pragma unroll
  for (int jj = 0; jj < 8; ++jj) {
    unsigned short hb = bf16rn(p[jj]);
    hi[jj] = hb;
    lo[jj] = bf16rn(p[jj] - __uint_as_float((unsigned)hb << 16));
  }
  const int t16 = r >> 4, rr = r & 15, kc = k8 >> 2, kq = k8 & 3;
  const size_t elem = (((size_t)(t16 * 32 + kc)) * 64 + ((kq << 4) | rr)) * 8;
  uint4 vh, vl;
  vh.x = hi[0] | (hi[1] << 16); vh.y = hi[2] | (hi[3] << 16);
  vh.z = hi[4] | (hi[5] << 16); vh.w = hi[6] | (hi[7] << 16);
  vl.x = lo[0] | (lo[1] << 16); vl.y = lo[2] | (lo[3] << 16);
  vl.z = lo[4] | (lo[5] << 16); vl.w = lo[6] | (lo[7] << 16);
  *(uint4*)(Yh + elem) = vh;
  *(uint4*)(Yl + elem) = vl;
}

extern "C" void kernel_launch(void* const* d_in, const int* in_sizes, int n_in,
                              void* d_out, int out_size, void* d_ws, size_t ws_size,
                              hipStream_t stream) {
  (void)in_sizes; (void)n_in; (void)out_size; (void)ws_size;
  const float* x           = (const float*)d_in[0];
  const float* w_attn      = (const float*)d_in[1];
  const float* w_proj      = (const float*)d_in[2];
  const float* w_gate      = (const float*)d_in[3];
  const float* span_params = (const float*)d_in[4];
  float* out = (float*)d_out;

  char* ws = (char*)d_ws;
  const size_t MB = 1024 * 1024;
  float* q     = (float*)(ws);            // 8 MB (qfrag; P0 after attn)
  float* k     = (float*)(ws + 8 * MB);   // 8 MB (kfrag; P1 after attn)
  float* v     = (float*)(ws + 16 * MB);  // 8 MB (P2 after attn)
  float* gate  = (float*)(ws + 24 * MB);  // 8 MB
  float* y_att = (float*)(ws + 32 * MB);  // 8 MB (P3 after gate_mul)
  unsigned short* xf_h  = (unsigned short*)(ws + 40 * MB);  // 4 MB
  unsigned short* xf_l  = (unsigned short*)(ws + 44 * MB);  // 4 MB
  unsigned short* wqg_h = (unsigned short*)(ws + 48 * MB);  // 8 MB
  unsigned short* wqg_l = (unsigned short*)(ws + 56 * MB);  // 8 MB
  unsigned short* wfp_h = (unsigned short*)(ws + 64 * MB);  // 2 MB
  unsigned short* wfp_l = (unsigned short*)(ws + 66 * MB);  // 2 MB
  unsigned short* ygf_h = (unsigned short*)(ws + 68 * MB);  // 4 MB
  unsigned short* ygf_l = (unsigned short*)(ws + 72 * MB);  // 4 MB
  float2* rope_tab = (float2*)(ws + 76 * MB);               // 0.5 MB
  unsigned* Sbuf = (unsigned*)(ws + 80 * MB);               // 64 MiB key stripe
  float* P0 = q;   // dead after attn
  float* P1 = k;
  float* P2 = v;
  float* P3 = y_att;  // dead after gate_mul

  convert_all_kernel<<<3840, 256, 0, stream>>>(
      x, w_attn, w_gate, w_proj, xf_h, xf_l, wqg_h, wqg_l, wfp_h, wfp_l, rope_tab);
  mgemm_qkvg_kernel<<<dim3(32, 16), 256, 0, stream>>>(
      xf_h, xf_l, wqg_h, wqg_l, q, k, v, gate);
  prep_frag_kernel<<<dim3(T_DIM / 16, H_DIM, 2), 64, 0, stream>>>(q, k, rope_tab);
  // attention: 4 stripes of 512 queries; 64 MB key buffer stays L3-resident
  for (int s = 0; s < 4; ++s) {
    score_kernel<<<dim3(8, STRIPE / 16, H_DIM), 256, 0, stream>>>(
        q, k, Sbuf, s * STRIPE);
    select_kernel<<<dim3(STRIPE / 4, H_DIM), 256, 0, stream>>>(
        Sbuf, v, span_params, y_att, s * STRIPE);
  }
  gate_mul_frag_kernel<<<T_DIM / 2, 256, 0, stream>>>(y_att, gate, ygf_h, ygf_l);
  mgemm_proj_kernel<<<dim3(8, 16, 4), 256, 0, stream>>>(
      ygf_h, ygf_l, wfp_h, wfp_l, P0, P1, P2, P3);
  add4_kernel<<<(T_DIM * C_DIM) / 1024, 256, 0, stream>>>(P0, P1, P2, P3, out);
}

// Round 13
// 354.319 us; speedup vs baseline: 1.1607x; 1.1607x over previous
//
#include <hip/hip_runtime.h>
#include <math.h>

#define T_DIM 2048
#define C_DIM 1024
#define H_DIM 16
#define HD 64
#define TOPK_K 64
#define QTILE 4
#define LCAP 128

typedef __attribute__((ext_vector_type(8))) __bf16 bf16x8;
typedef __attribute__((ext_vector_type(4))) float f32x4;

__device__ __forceinline__ unsigned short bf16rn(float x) {
  unsigned u = __float_as_uint(x);
  return (unsigned short)((u + 0x7FFFu + ((u >> 16) & 1u)) >> 16);
}
__device__ __forceinline__ unsigned f2u(float f) {
  unsigned u = __float_as_uint(f);
  return (u & 0x80000000u) ? ~u : (u | 0x80000000u);
}
__device__ __forceinline__ float u2f(unsigned u) {
  unsigned v = (u & 0x80000000u) ? (u & 0x7FFFFFFFu) : ~u;
  return __uint_as_float(v);
}
__device__ __forceinline__ bf16x8 ld_frag(const uint4* p) {
  uint4 u = *p;
  return __builtin_bit_cast(bf16x8, u);
}
#define PAD_KEY 0x007FFFFFu   // f2u(-INF); real raw scores always exceed this

// ------- fused fp32 -> frag-global bf16 hi/lo converter + rope table --------
__global__ __launch_bounds__(256) void convert_all_kernel(
    const float* __restrict__ x, const float* __restrict__ wa,
    const float* __restrict__ wg, const float* __restrict__ wp,
    unsigned short* __restrict__ xh, unsigned short* __restrict__ xl,
    unsigned short* __restrict__ wqgh, unsigned short* __restrict__ wqgl,
    unsigned short* __restrict__ wph, unsigned short* __restrict__ wpl,
    float2* __restrict__ tab)
{
  const int tid = blockIdx.x * 256 + threadIdx.x;
  const int k8 = tid & 127, r = tid >> 7;
  if (r >= 7168) {   // rope sincos table tail: 512 r-slots x 128 = 65536
    const int e = ((r - 7168) << 7) | k8;
    const int t = e >> 5, d = e & 31;
    double invf = exp(-(double)d * (log(10000.0) / 32.0));
    double ang = (double)t * invf;
    tab[e] = make_float2((float)cos(ang), (float)sin(ang));
    return;
  }
  const float* src;
  unsigned short *Dh, *Dl;
  int srow, drow;
  if (r < 2048)      { src = x;  Dh = xh;   Dl = xl;   srow = r;        drow = r; }
  else if (r < 5120) { src = wa; Dh = wqgh; Dl = wqgl; srow = r - 2048; drow = r - 2048; }
  else if (r < 6144) { src = wg; Dh = wqgh; Dl = wqgl; srow = r - 5120; drow = r - 2048; }
  else               { src = wp; Dh = wph;  Dl = wpl;  srow = r - 6144; drow = r - 6144; }
  const float* s = src + ((size_t)srow << 10) + (k8 << 3);
  float4 a = *(const float4*)s;
  float4 b = *(const float4*)(s + 4);
  float xs[8] = {a.x, a.y, a.z, a.w, b.x, b.y, b.z, b.w};
  unsigned hi[8], lo[8];
#pragma unroll
  for (int jj = 0; jj < 8; ++jj) {
    unsigned short hb = bf16rn(xs[jj]);
    hi[jj] = hb;
    lo[jj] = bf16rn(xs[jj] - __uint_as_float((unsigned)hb << 16));
  }
  const int t16 = drow >> 4, rr = drow & 15, kc = k8 >> 2, kq = k8 & 3;
  const size_t elem = (((size_t)(t16 * 32 + kc)) * 64 + ((kq << 4) | rr)) * 8;
  uint4 vh, vl;
  vh.x = hi[0] | (hi[1] << 16); vh.y = hi[2] | (hi[3] << 16);
  vh.z = hi[4] | (hi[5] << 16); vh.w = hi[6] | (hi[7] << 16);
  vl.x = lo[0] | (lo[1] << 16); vl.y = lo[2] | (lo[3] << 16);
  vl.z = lo[4] | (lo[5] << 16); vl.w = lo[6] | (lo[7] << 16);
  *(uint4*)(Dh + elem) = vh;
  *(uint4*)(Dl + elem) = vl;
}

// ---------------- split-bf16 MFMA GEMM machinery ----------------
__device__ __forceinline__ void gld_lds16(const unsigned short* g, unsigned short* l) {
  __builtin_amdgcn_global_load_lds(
      (const __attribute__((address_space(1))) unsigned int*)g,
      (__attribute__((address_space(3))) unsigned int*)l, 16, 0, 0);
}

// qkv+gate GEMM, 64x128 tiles: grid (32, 32), 4 blocks/CU.
// Wave w computes A-tile16 w x all 8 B-tiles.
__global__ __launch_bounds__(256, 4) void mgemm_qkvg_kernel(
    const unsigned short* __restrict__ Ah, const unsigned short* __restrict__ Al,
    const unsigned short* __restrict__ Bh, const unsigned short* __restrict__ Bl,
    float* __restrict__ Cq, float* __restrict__ Ck, float* __restrict__ Cv,
    float* __restrict__ Cg)
{
  __shared__ __align__(16) unsigned short As[2 * 4 * 512];  // 8 KB
  __shared__ __align__(16) unsigned short Bs[2 * 8 * 512];  // 16 KB
  const int tid = threadIdx.x, lane = tid & 63, w = tid >> 6;
  const int mt0 = blockIdx.y << 2;   // 4 tiles16 of A rows
  const int nt0 = blockIdx.x << 3;   // 8 tiles16 of B rows

  f32x4 acc[8];
#pragma unroll
  for (int j = 0; j < 8; ++j) acc[j] = (f32x4){0.f, 0.f, 0.f, 0.f};

  for (int kc = 0; kc < 32; ++kc) {
#pragma unroll
    for (int li = 0; li < 6; ++li) {
      const int gi = w * 6 + li;           // 0..23
      const int isB = gi >= 8;
      const int t  = isB ? ((gi - 8) & 7) : (gi & 3);
      const int hl = isB ? ((gi - 8) >> 3) : (gi >> 2);
      const unsigned short* gbase = isB ? (hl ? Bl : Bh) : (hl ? Al : Ah);
      const int tg = (isB ? nt0 : mt0) + t;
      const unsigned short* g = gbase + (((size_t)(tg * 32 + kc) << 6) + lane) * 8;
      unsigned short* l = isB ? (Bs + hl * 4096 + t * 512) : (As + hl * 2048 + t * 512);
      gld_lds16(g, l);
    }
    __syncthreads();
    bf16x8 ah = *(const bf16x8*)&As[w * 512 + lane * 8];
    bf16x8 al = *(const bf16x8*)&As[2048 + w * 512 + lane * 8];
#pragma unroll
    for (int j = 0; j < 8; ++j) {
      bf16x8 bh = *(const bf16x8*)&Bs[j * 512 + lane * 8];
      bf16x8 bl = *(const bf16x8*)&Bs[4096 + j * 512 + lane * 8];
      acc[j] = __builtin_amdgcn_mfma_f32_16x16x32_bf16(ah, bh, acc[j], 0, 0, 0);
      acc[j] = __builtin_amdgcn_mfma_f32_16x16x32_bf16(ah, bl, acc[j], 0, 0, 0);
      acc[j] = __builtin_amdgcn_mfma_f32_16x16x32_bf16(al, bh, acc[j], 0, 0, 0);
    }
    __syncthreads();
  }

  const int col = lane & 15, quad = lane >> 4;
  const int mbase = (blockIdx.y << 6) + (w << 4);
#pragma unroll
  for (int j = 0; j < 8; ++j) {
    const int ncol = (blockIdx.x << 7) + (j << 4);
    const int which = ncol >> 10;
    if (which < 3) {
      const int h = (ncol & 1023) >> 6;
      float* dst = (which == 0) ? Cq : (which == 1) ? Ck : Cv;
      float* base = dst + (((size_t)h * T_DIM) << 6) + (ncol & 63) + col;
#pragma unroll
      for (int reg = 0; reg < 4; ++reg) {
        const int m = mbase + quad * 4 + reg;
        base[(size_t)m << 6] = acc[j][reg];
      }
    } else {
      const int cb = (ncol & 1023) + col;
#pragma unroll
      for (int reg = 0; reg < 4; ++reg) {
        const int m = mbase + quad * 4 + reg;
        float vv = acc[j][reg];
        Cg[((size_t)m << 10) + cb] = vv / (1.f + expf(-vv));
      }
    }
  }
}

// proj GEMM, 64x128 tiles, split-K x2: grid (8, 32, 2).
__global__ __launch_bounds__(256, 4) void mgemm_proj_kernel(
    const unsigned short* __restrict__ Ah, const unsigned short* __restrict__ Al,
    const unsigned short* __restrict__ Bh, const unsigned short* __restrict__ Bl,
    float* __restrict__ P0, float* __restrict__ P1)
{
  __shared__ __align__(16) unsigned short As[2 * 4 * 512];  // 8 KB
  __shared__ __align__(16) unsigned short Bs[2 * 8 * 512];  // 16 KB
  const int tid = threadIdx.x, lane = tid & 63, w = tid >> 6;
  const int mt0 = blockIdx.y << 2;
  const int nt0 = blockIdx.x << 3;
  const int kc0 = blockIdx.z << 4;
  float* Cout = blockIdx.z ? P1 : P0;

  f32x4 acc[8];
#pragma unroll
  for (int j = 0; j < 8; ++j) acc[j] = (f32x4){0.f, 0.f, 0.f, 0.f};

  for (int kc = kc0; kc < kc0 + 16; ++kc) {
#pragma unroll
    for (int li = 0; li < 6; ++li) {
      const int gi = w * 6 + li;
      const int isB = gi >= 8;
      const int t  = isB ? ((gi - 8) & 7) : (gi & 3);
      const int hl = isB ? ((gi - 8) >> 3) : (gi >> 2);
      const unsigned short* gbase = isB ? (hl ? Bl : Bh) : (hl ? Al : Ah);
      const int tg = (isB ? nt0 : mt0) + t;
      const unsigned short* g = gbase + (((size_t)(tg * 32 + kc) << 6) + lane) * 8;
      unsigned short* l = isB ? (Bs + hl * 4096 + t * 512) : (As + hl * 2048 + t * 512);
      gld_lds16(g, l);
    }
    __syncthreads();
    bf16x8 ah = *(const bf16x8*)&As[w * 512 + lane * 8];
    bf16x8 al = *(const bf16x8*)&As[2048 + w * 512 + lane * 8];
#pragma unroll
    for (int j = 0; j < 8; ++j) {
      bf16x8 bh = *(const bf16x8*)&Bs[j * 512 + lane * 8];
      bf16x8 bl = *(const bf16x8*)&Bs[4096 + j * 512 + lane * 8];
      acc[j] = __builtin_amdgcn_mfma_f32_16x16x32_bf16(ah, bh, acc[j], 0, 0, 0);
      acc[j] = __builtin_amdgcn_mfma_f32_16x16x32_bf16(ah, bl, acc[j], 0, 0, 0);
      acc[j] = __builtin_amdgcn_mfma_f32_16x16x32_bf16(al, bh, acc[j], 0, 0, 0);
    }
    __syncthreads();
  }

  const int col = lane & 15, quad = lane >> 4;
  const int mbase = (blockIdx.y << 6) + (w << 4);
  const int nbase = blockIdx.x << 7;
#pragma unroll
  for (int j = 0; j < 8; ++j)
#pragma unroll
    for (int reg = 0; reg < 4; ++reg) {
      const int m = mbase + quad * 4 + reg;
      Cout[((size_t)m << 10) + nbase + (j << 4) + col] = acc[j][reg];
    }
}

__global__ __launch_bounds__(256) void add2_kernel(
    const float* __restrict__ P0, const float* __restrict__ P1,
    float* __restrict__ out)
{
  const int i = (blockIdx.x * 256 + threadIdx.x) << 2;
  float4 a = *(const float4*)(P0 + i);
  float4 b = *(const float4*)(P1 + i);
  float4 o = {a.x + b.x, a.y + b.y, a.z + b.z, a.w + b.w};
  *(float4*)(out + i) = o;
}

// ------- RoPE (table-driven) + bf16 hi/lo split into attention frag layout --
__global__ __launch_bounds__(64) void prep_frag_kernel(
    float* __restrict__ qb, float* __restrict__ kb,
    const float2* __restrict__ tab)
{
  float* buf = blockIdx.z ? kb : qb;
  const int lane = threadIdx.x;
  const int t16 = blockIdx.x, h = blockIdx.y;
  const int nr = lane & 15, quad = lane >> 4;
  const int t = (t16 << 4) + nr;
  const float* row = buf + ((size_t)(h * T_DIM + t) << 6);
  const int d0 = quad << 3;
  float4 a0 = *(const float4*)(row + d0);
  float4 a1 = *(const float4*)(row + d0 + 4);
  float4 b0 = *(const float4*)(row + 32 + d0);
  float4 b1 = *(const float4*)(row + 32 + d0 + 4);
  float x0[8] = {a0.x, a0.y, a0.z, a0.w, a1.x, a1.y, a1.z, a1.w};
  float x1[8] = {b0.x, b0.y, b0.z, b0.w, b1.x, b1.y, b1.z, b1.w};
  const float2* tb = tab + t * 32 + d0;
  unsigned short h0[8], l0[8], h1[8], l1[8];
#pragma unroll
  for (int jj = 0; jj < 8; ++jj) {
    float2 cs2 = tb[jj];
    float o0 = fmaf(x0[jj], cs2.x, -x1[jj] * cs2.y);
    float o1 = fmaf(x1[jj], cs2.x, x0[jj] * cs2.y);
    unsigned short hb = bf16rn(o0);
    h0[jj] = hb;
    l0[jj] = bf16rn(o0 - __uint_as_float((unsigned)hb << 16));
    hb = bf16rn(o1);
    h1[jj] = hb;
    l1[jj] = bf16rn(o1 - __uint_as_float((unsigned)hb << 16));
  }
  char* base = (char*)buf + (((size_t)(h * 128 + t16)) << 12);
  uint4 v;
  v.x = (unsigned)h0[0] | ((unsigned)h0[1] << 16);
  v.y = (unsigned)h0[2] | ((unsigned)h0[3] << 16);
  v.z = (unsigned)h0[4] | ((unsigned)h0[5] << 16);
  v.w = (unsigned)h0[6] | ((unsigned)h0[7] << 16);
  ((uint4*)base)[lane] = v;
  v.x = (unsigned)h1[0] | ((unsigned)h1[1] << 16);
  v.y = (unsigned)h1[2] | ((unsigned)h1[3] << 16);
  v.z = (unsigned)h1[4] | ((unsigned)h1[5] << 16);
  v.w = (unsigned)h1[6] | ((unsigned)h1[7] << 16);
  ((uint4*)(base + 1024))[lane] = v;
  v.x = (unsigned)l0[0] | ((unsigned)l0[1] << 16);
  v.y = (unsigned)l0[2] | ((unsigned)l0[3] << 16);
  v.z = (unsigned)l0[4] | ((unsigned)l0[5] << 16);
  v.w = (unsigned)l0[6] | ((unsigned)l0[7] << 16);
  ((uint4*)(base + 2048))[lane] = v;
  v.x = (unsigned)l1[0] | ((unsigned)l1[1] << 16);
  v.y = (unsigned)l1[2] | ((unsigned)l1[3] << 16);
  v.z = (unsigned)l1[4] | ((unsigned)l1[5] << 16);
  v.w = (unsigned)l1[6] | ((unsigned)l1[7] << 16);
  ((uint4*)(base + 3072))[lane] = v;
}

// ---------------- attention (round-10 monolithic, QTILE=4) ----------------
__global__ __launch_bounds__(256) void attn_kernel(
    const float* __restrict__ qfrag, const float* __restrict__ kfrag,
    const float* __restrict__ v, const float* __restrict__ span_params,
    float* __restrict__ y)
{
  __shared__ __align__(16) char smem[QTILE * 1024 * 4];
  float* sBase = (float*)smem;
  unsigned* histB = (unsigned*)smem;             // 4 KB
  int* listJB = (int*)(smem + 4096);             // 2 KB
  unsigned* listUB = (unsigned*)(smem + 6144);   // 2 KB

  const int tid = threadIdx.x;
  const int lane = tid & 63;
  const int w = tid >> 6;
  const int bx = gridDim.x - 1 - blockIdx.x;     // LPT: heavy blocks first
  const int q0 = bx << 2;
  const int h = blockIdx.y;
  const int qi = q0 + w;
  const int n = qi + 1;
  const float* vh = v + (((size_t)h * T_DIM) << 6);
  const int col = lane & 15, quad = lane >> 4;

  const int qt = q0 >> 4;
  const int qsel = (q0 & 15) >> 2;
  const uint4* qf = (const uint4*)((const char*)qfrag + (((size_t)(h * 128 + qt)) << 12));
  bf16x8 Ah0 = ld_frag(qf + lane);
  bf16x8 Ah1 = ld_frag(qf + 64 + lane);
  bf16x8 Al0 = ld_frag(qf + 128 + lane);
  bf16x8 Al1 = ld_frag(qf + 192 + lane);

  unsigned uk[32];

#pragma unroll
  for (int ph = 0; ph < 2; ++ph) {
    const int tlo = ph << 6;
    const int thi = (qt < tlo + 63) ? qt : (tlo + 63);
    for (int tf = tlo + w; tf <= thi; tf += 4) {
      const uint4* kf = (const uint4*)((const char*)kfrag + (((size_t)(h * 128 + tf)) << 12));
      bf16x8 Bh0 = ld_frag(kf + lane);
      bf16x8 Bh1 = ld_frag(kf + 64 + lane);
      bf16x8 Bl0 = ld_frag(kf + 128 + lane);
      bf16x8 Bl1 = ld_frag(kf + 192 + lane);
      f32x4 acc = {0.f, 0.f, 0.f, 0.f};
      acc = __builtin_amdgcn_mfma_f32_16x16x32_bf16(Ah0, Bh0, acc, 0, 0, 0);
      acc = __builtin_amdgcn_mfma_f32_16x16x32_bf16(Ah0, Bl0, acc, 0, 0, 0);
      acc = __builtin_amdgcn_mfma_f32_16x16x32_bf16(Al0, Bh0, acc, 0, 0, 0);
      acc = __builtin_amdgcn_mfma_f32_16x16x32_bf16(Ah1, Bh1, acc, 0, 0, 0);
      acc = __builtin_amdgcn_mfma_f32_16x16x32_bf16(Ah1, Bl1, acc, 0, 0, 0);
      acc = __builtin_amdgcn_mfma_f32_16x16x32_bf16(Al1, Bh1, acc, 0, 0, 0);
      if (quad == qsel) {
        const int jcol = (tf << 4) + col;
#pragma unroll
        for (int r = 0; r < 4; ++r)
          if (jcol <= q0 + r) sBase[r * 1024 + (jcol & 1023)] = acc[r];
      }
    }
    __syncthreads();
#pragma unroll
    for (int cc = 0; cc < 2; ++cc) {
      const int c = (ph << 1) + cc;
      if ((c << 9) < n) {
#pragma unroll
        for (int i = 0; i < 8; ++i) {
          const int j = (((c << 3) + i) << 6) + lane;
          uk[(c << 3) + i] = (j < n) ? f2u(sBase[w * 1024 + (j & 1023)]) : PAD_KEY;
        }
      } else {
#pragma unroll
        for (int i = 0; i < 8; ++i) uk[(c << 3) + i] = PAD_KEY;
      }
    }
    __syncthreads();
  }

  unsigned* hist = histB + (w << 8);
  int* listJ = listJB + (w << 7);
  unsigned* listU = listUB + (w << 7);
  const float span = 2048.f * fminf(fmaxf(span_params[h], 0.f), 1.f);

  unsigned umax = 0;
#pragma unroll
  for (int i = 0; i < 32; ++i) umax = max(umax, uk[i]);
#pragma unroll
  for (int off = 32; off > 0; off >>= 1)
    umax = max(umax, (unsigned)__shfl_xor((int)umax, off, 64));
  const float mraw = u2f(umax);

  unsigned thresh_u = 0;
  if (n > TOPK_K) {
    unsigned prefix = 0;
    unsigned want = TOPK_K;
    for (int shift = 24; shift >= 0; shift -= 8) {
      uint4 z4 = {0u, 0u, 0u, 0u};
      *(uint4*)&hist[lane << 2] = z4;
      __threadfence_block();
      const unsigned pm = (shift == 24) ? 0u : (0xFFFFFFFFu << (shift + 8));
#pragma unroll
      for (int c = 0; c < 4; ++c) {
        if ((c << 9) < n) {
#pragma unroll
          for (int i = 0; i < 8; ++i) {
            const unsigned u = uk[(c << 3) + i];
            if (u > PAD_KEY && (u & pm) == prefix)
              atomicAdd(&hist[(u >> shift) & 255u], 1u);
          }
        }
      }
      __threadfence_block();
      uint4 hv = *(const uint4*)&hist[lane << 2];
      unsigned loc = hv.x + hv.y + hv.z + hv.w;
      unsigned suf = loc;
#pragma unroll
      for (int off = 1; off < 64; off <<= 1) {
        unsigned t = __shfl_down(suf, off, 64);
        suf += (lane + off < 64) ? t : 0u;
      }
      unsigned sufE = suf - loc;
      unsigned S3 = sufE + hv.w;
      unsigned S2 = S3 + hv.z;
      unsigned S1 = S2 + hv.y;
      unsigned S0 = S1 + hv.x;
      const unsigned wt = want;
      int found = 0;
      unsigned pk = 0;
      if (S0 >= wt && S1 < wt)
        { found = 1; pk = ((unsigned)(4*lane+0) << 16) | ((S0 == wt) ? 0x8000u : 0u) | (wt - S1); }
      if (S1 >= wt && S2 < wt)
        { found = 1; pk = ((unsigned)(4*lane+1) << 16) | ((S1 == wt) ? 0x8000u : 0u) | (wt - S2); }
      if (S2 >= wt && S3 < wt)
        { found = 1; pk = ((unsigned)(4*lane+2) << 16) | ((S2 == wt) ? 0x8000u : 0u) | (wt - S3); }
      if (S3 >= wt && sufE < wt)
        { found = 1; pk = ((unsigned)(4*lane+3) << 16) | ((S3 == wt) ? 0x8000u : 0u) | (wt - sufE); }
      unsigned long long mk = __ballot(found);
      int src = __ffsll(mk) - 1;
      pk = __shfl(pk, src, 64);
      prefix |= (pk >> 16) << shift;
      want = pk & 0x7FFFu;
      if (pk & 0x8000u) break;
    }
    thresh_u = prefix;
  }

  int cnt_run = 0;
#pragma unroll
  for (int c = 0; c < 4; ++c) {
    if ((c << 9) < n) {
#pragma unroll
      for (int i = 0; i < 8; ++i) {
        const int j = (((c << 3) + i) << 6) + lane;
        const unsigned u = uk[(c << 3) + i];
        const bool keep = (u >= thresh_u) && (u > PAD_KEY);
        unsigned long long mb = __ballot(keep);
        if (keep) {
          int pos = cnt_run + (int)__popcll(mb & ((1ull << lane) - 1ull));
          if (pos < LCAP) { listJ[pos] = j; listU[pos] = u; }
        }
        cnt_run += (int)__popcll(mb);
      }
    }
  }
  const int cnt = min(cnt_run, LCAP);
  __threadfence_block();

  float Zl = 0.f, Ul = 0.f;
  for (int e = lane; e < cnt; e += 64) {
    const unsigned u = listU[e];
    const int j = listJ[e];
    const float wv = __expf((u2f(u) - mraw) * 0.125f);
    const float dist = (float)(qi - j);
    const float msk = fminf(fmaxf((32.f + span - dist) * (1.f / 32.f), 0.f), 1.f);
    const float wm = wv * msk;
    Zl += wv;
    Ul += wm;
    listU[e] = __float_as_uint(wm);
  }
#pragma unroll
  for (int off = 32; off > 0; off >>= 1) {
    Zl += __shfl_xor(Zl, off, 64);
    Ul += __shfl_xor(Ul, off, 64);
  }
  const float scale = 1.f / (Ul + 1e-8f * Zl);
  __threadfence_block();

  const int g = lane >> 4;
  const int d4 = col << 2;
  float4 acc4 = {0.f, 0.f, 0.f, 0.f};
  for (int e0 = 0; e0 < cnt; e0 += 4) {
    int e = e0 + g;
    float wm = 0.f;
    int idx = 0;
    if (e < cnt) { idx = listJ[e]; wm = __uint_as_float(listU[e]); }
    const float4 vv = *(const float4*)(vh + ((size_t)idx << 6) + d4);
    acc4.x = fmaf(wm, vv.x, acc4.x);
    acc4.y = fmaf(wm, vv.y, acc4.y);
    acc4.z = fmaf(wm, vv.z, acc4.z);
    acc4.w = fmaf(wm, vv.w, acc4.w);
  }
#pragma unroll
  for (int off = 16; off <= 32; off <<= 1) {
    acc4.x += __shfl_xor(acc4.x, off, 64);
    acc4.y += __shfl_xor(acc4.y, off, 64);
    acc4.z += __shfl_xor(acc4.z, off, 64);
    acc4.w += __shfl_xor(acc4.w, off, 64);
  }
  if (g == 0) {
    float4 o = {acc4.x * scale, acc4.y * scale, acc4.z * scale, acc4.w * scale};
    *(float4*)(y + ((((size_t)h * T_DIM) + qi) << 6) + d4) = o;
  }
}

// -------- gating: y_att (head-major) * gate -> ygf frag-global hi/lo --------
__global__ __launch_bounds__(256) void gate_mul_frag_kernel(
    const float* __restrict__ y_att, const float* __restrict__ gate,
    unsigned short* __restrict__ Yh, unsigned short* __restrict__ Yl)
{
  const int tid = blockIdx.x * 256 + threadIdx.x;
  const int k8 = tid & 127, r = tid >> 7;
  const int c0 = k8 << 3;
  const int h = c0 >> 6, d0 = c0 & 63;
  const float* ya = y_att + ((size_t)(h * T_DIM + r) << 6) + d0;
  const float* ga = gate + ((size_t)r << 10) + c0;
  float4 y0 = *(const float4*)ya;
  float4 y1 = *(const float4*)(ya + 4);
  float4 g0 = *(const float4*)ga;
  float4 g1 = *(const float4*)(ga + 4);
  float p[8] = {y0.x * g0.x, y0.y * g0.y, y0.z * g0.z, y0.w * g0.w,
                y1.x * g1.x, y1.y * g1.y, y1.z * g1.z, y1.w * g1.w};
  unsigned hi[8], lo[8];
#pragma unroll
  for (int jj = 0; jj < 8; ++jj) {
    unsigned short hb = bf16rn(p[jj]);
    hi[jj] = hb;
    lo[jj] = bf16rn(p[jj] - __uint_as_float((unsigned)hb << 16));
  }
  const int t16 = r >> 4, rr = r & 15, kc = k8 >> 2, kq = k8 & 3;
  const size_t elem = (((size_t)(t16 * 32 + kc)) * 64 + ((kq << 4) | rr)) * 8;
  uint4 vh, vl;
  vh.x = hi[0] | (hi[1] << 16); vh.y = hi[2] | (hi[3] << 16);
  vh.z = hi[4] | (hi[5] << 16); vh.w = hi[6] | (hi[7] << 16);
  vl.x = lo[0] | (lo[1] << 16); vl.y = lo[2] | (lo[3] << 16);
  vl.z = lo[4] | (lo[5] << 16); vl.w = lo[6] | (lo[7] << 16);
  *(uint4*)(Yh + elem) = vh;
  *(uint4*)(Yl + elem) = vl;
}

extern "C" void kernel_launch(void* const* d_in, const int* in_sizes, int n_in,
                              void* d_out, int out_size, void* d_ws, size_t ws_size,
                              hipStream_t stream) {
  (void)in_sizes; (void)n_in; (void)out_size; (void)ws_size;
  const float* x           = (const float*)d_in[0];
  const float* w_attn      = (const float*)d_in[1];
  const float* w_proj      = (const float*)d_in[2];
  const float* w_gate      = (const float*)d_in[3];
  const float* span_params = (const float*)d_in[4];
  float* out = (float*)d_out;

  char* ws = (char*)d_ws;
  const size_t MB = 1024 * 1024;
  float* q     = (float*)(ws);            // 8 MB (qfrag; P0 after attn)
  float* k     = (float*)(ws + 8 * MB);   // 8 MB (kfrag; P1 after attn)
  float* v     = (float*)(ws + 16 * MB);  // 8 MB
  float* gate  = (float*)(ws + 24 * MB);  // 8 MB
  float* y_att = (float*)(ws + 32 * MB);  // 8 MB
  unsigned short* xf_h  = (unsigned short*)(ws + 40 * MB);  // 4 MB
  unsigned short* xf_l  = (unsigned short*)(ws + 44 * MB);  // 4 MB
  unsigned short* wqg_h = (unsigned short*)(ws + 48 * MB);  // 8 MB
  unsigned short* wqg_l = (unsigned short*)(ws + 56 * MB);  // 8 MB
  unsigned short* wfp_h = (unsigned short*)(ws + 64 * MB);  // 2 MB
  unsigned short* wfp_l = (unsigned short*)(ws + 66 * MB);  // 2 MB
  unsigned short* ygf_h = (unsigned short*)(ws + 68 * MB);  // 4 MB
  unsigned short* ygf_l = (unsigned short*)(ws + 72 * MB);  // 4 MB
  float2* rope_tab = (float2*)(ws + 76 * MB);               // 0.5 MB
  float* P0 = q;   // dead after attn
  float* P1 = k;

  convert_all_kernel<<<3840, 256, 0, stream>>>(
      x, w_attn, w_gate, w_proj, xf_h, xf_l, wqg_h, wqg_l, wfp_h, wfp_l, rope_tab);
  mgemm_qkvg_kernel<<<dim3(32, 32), 256, 0, stream>>>(
      xf_h, xf_l, wqg_h, wqg_l, q, k, v, gate);
  prep_frag_kernel<<<dim3(T_DIM / 16, H_DIM, 2), 64, 0, stream>>>(q, k, rope_tab);
  attn_kernel<<<dim3(T_DIM / QTILE, H_DIM), 256, 0, stream>>>(
      q, k, v, span_params, y_att);
  gate_mul_frag_kernel<<<T_DIM / 2, 256, 0, stream>>>(y_att, gate, ygf_h, ygf_l);
  mgemm_proj_kernel<<<dim3(8, 32, 2), 256, 0, stream>>>(
      ygf_h, ygf_l, wfp_h, wfp_l, P0, P1);
  add2_kernel<<<(T_DIM * C_DIM) / 1024, 256, 0, stream>>>(P0, P1, out);
}